// Round 4
// baseline (34043.756 us; speedup 1.0000x reference)
//
#include <hip/hip_runtime.h>
#include <hip/hip_fp16.h>

#define LOG2E 1.44269504088896340736f
#define BB 256
#define TT 128
#define SS 128
#define UU 256

// ---------------- parameter precompute ----------------
// sigmoid(sigma*(v-mu)) = 1/(1+2^(a*v+b)), a=-sigma*log2e, b=sigma*mu*log2e
// rab[i*UU+j]      : uint = half2(a,b)
// rw2[(i/2)*UU+j]  : uint = half2(wsig_i, wsig_{i+1}),  wsig = softplus(w)*erev
// num += wsig*s ; den += |wsig|*s   (abs is a free VOP3 modifier)
__global__ __launch_bounds__(256) void prep_kernel(
    const float* __restrict__ sensory_w, const float* __restrict__ sensory_mu,
    const float* __restrict__ sensory_sigma, const float* __restrict__ sensory_erev,
    const float* __restrict__ w, const float* __restrict__ mu,
    const float* __restrict__ sigma, const float* __restrict__ erev,
    const float* __restrict__ gleak, const float* __restrict__ vleak,
    const float* __restrict__ cm,
    unsigned int* __restrict__ rab, unsigned int* __restrict__ rw2,
    unsigned int* __restrict__ sab, unsigned int* __restrict__ sw2,
    float* __restrict__ cmt, float* __restrict__ gnum, float* __restrict__ cden)
{
    int e = blockIdx.x * 256 + threadIdx.x;
    int i = e >> 8;
    if (e < UU * UU) {
        float sg = sigma[e], m = mu[e];
        __half2 ab = __floats2half2_rn(-sg * LOG2E, sg * m * LOG2E);
        rab[e] = *(unsigned int*)&ab;
        if ((i & 1) == 0) {
            float w0 = log1pf(expf(w[e])) * erev[e];
            float w1 = log1pf(expf(w[e + UU])) * erev[e + UU];
            __half2 wp = __floats2half2_rn(w0, w1);
            rw2[(i >> 1) * UU + (e & (UU - 1))] = *(unsigned int*)&wp;
        }
    }
    if (e < SS * UU) {
        float sg = sensory_sigma[e], m = sensory_mu[e];
        __half2 ab = __floats2half2_rn(-sg * LOG2E, sg * m * LOG2E);
        sab[e] = *(unsigned int*)&ab;
        if ((i & 1) == 0) {
            float w0 = log1pf(expf(sensory_w[e])) * sensory_erev[e];
            float w1 = log1pf(expf(sensory_w[e + UU])) * sensory_erev[e + UU];
            __half2 wp = __floats2half2_rn(w0, w1);
            sw2[(i >> 1) * UU + (e & (UU - 1))] = *(unsigned int*)&wp;
        }
    }
    if (e < UU) {
        float gl = log1pf(expf(gleak[e]));
        float c = log1pf(expf(cm[e])) * 6.0f;   // ODE_UNFOLDS=6, ts=1
        cmt[e] = c;
        gnum[e] = gl * vleak[e];
        cden[e] = c + gl + 1e-8f;
    }
}

// f32 sigmoid with f16 params: compiler folds half2float into v_fma_mix_f32
__device__ __forceinline__ float sigz(unsigned int ab, float vk) {
    __half2 h = *(__half2*)&ab;
    float z = fmaf(__half2float(__low2half(h)), vk, __half2float(__high2half(h)));
    float e = __builtin_amdgcn_exp2f(z);
    return __builtin_amdgcn_rcpf(1.0f + e);
}
__device__ __forceinline__ void accum(unsigned int w2, float s0, float s1,
                                      float& num, float& den) {
    __half2 h = *(__half2*)&w2;
    float w0 = __half2float(__low2half(h));
    float w1 = __half2float(__high2half(h));
    num = fmaf(w0, s0, num); den = fmaf(fabsf(w0), s0, den);
    num = fmaf(w1, s1, num); den = fmaf(fabsf(w1), s1, den);
}

#define RLF(IDX) __int_as_float(__builtin_amdgcn_readlane(__float_as_int(v), (IDX)))

// ---------------- main kernel: 1 block = 1 batch element, 16 waves ----------------
// wave (qi=wv&3, qj=wv>>2): column j = 64*qj + l.
// rows per wave: 48 in registers (48qi..48qi+47, 72 VGPRs) + 16 from LDS (192+16qi..+15).
// v lane-distributed: lane l holds v[u], u = l<48 ? 48qi+l : 192+16qi+(l-48).
// readlane broadcasts v; 1 barrier per unfold (double-buffered partials).
__global__ __launch_bounds__(1024, 4) void ltc_kernel(
    const float* __restrict__ x,
    const float* __restrict__ input_w, const float* __restrict__ input_b,
    const float* __restrict__ halt_w, const float* __restrict__ halt_b,
    const float* __restrict__ out_w, const float* __restrict__ out_b,
    const unsigned int* __restrict__ rab, const unsigned int* __restrict__ rw2,
    const unsigned int* __restrict__ sab, const unsigned int* __restrict__ sw2,
    const float* __restrict__ cmt_g, const float* __restrict__ gnum_g,
    const float* __restrict__ cden_g,
    float* __restrict__ readout, float* __restrict__ h_state, float* __restrict__ ponder_out)
{
    const int b = blockIdx.x, tid = threadIdx.x;
    const int wv = tid >> 6, l = tid & 63;
    const int qi = wv & 3, qj = wv >> 2;
    const int j = (qj << 6) + l;
    const int u = (l < 48) ? (48 * qi + l) : (192 + 16 * qi + (l - 48));

    __shared__ unsigned int ab_lds[64 * UU];   // 64 KB: ab rows 192..255
    __shared__ unsigned int w2_lds[32 * UU];   // 32 KB: w row-pairs 96..127
    __shared__ float2 part[2][4][UU];          // 16 KB (num,den) double-buffered
    __shared__ float xin_sh[SS];
    __shared__ float red[4];

    // stage LDS-resident rows (once)
    for (int m = 0; m < 16; ++m) ab_lds[m * 1024 + tid] = rab[192 * UU + m * 1024 + tid];
    for (int m = 0; m < 8; ++m)  w2_lds[m * 1024 + tid] = rw2[96 * UU + m * 1024 + tid];

    // register-resident rows (once): 48 + 24 = 72 VGPRs
    unsigned int rg_ab[48], rg_w2[24];
#pragma unroll
    for (int k = 0; k < 48; ++k) rg_ab[k] = rab[(48 * qi + k) * UU + j];
#pragma unroll
    for (int m = 0; m < 24; ++m) rg_w2[m] = rw2[(24 * qi + m) * UU + j];

    const float cmtu = cmt_g[u], gnu = gnum_g[u], cdu = cden_g[u];
    const float hwu = halt_w[u], owu = out_w[u], obu = out_b[u];
    const float hb = halt_b[0];
    float iw = 0.f, ibv = 0.f;
    if (tid < SS) { iw = input_w[tid]; ibv = input_b[tid]; }

    float v = 0.0f;
    float pond = 0.0f;
    __syncthreads();

    for (int t = 0; t < TT; ++t) {
        // ---- input mapping ----
        if (tid < SS) xin_sh[tid] = fmaf(x[((size_t)b * TT + t) * SS + tid], iw, ibv);
        __syncthreads();

        // ---- sensory partials: rows [32qi, 32qi+32), streamed from L2 ----
        {
            float num = 0.f, den = 0.f;
#pragma unroll 4
            for (int m = 0; m < 16; ++m) {
                int row = 32 * qi + 2 * m;
                unsigned int ab0 = sab[row * UU + j];
                unsigned int ab1 = sab[(row + 1) * UU + j];
                unsigned int wp  = sw2[(16 * qi + m) * UU + j];
                float s0 = sigz(ab0, xin_sh[row]);
                float s1 = sigz(ab1, xin_sh[row + 1]);
                accum(wp, s0, s1, num, den);
            }
            part[0][qi][j] = make_float2(num, den);
        }
        __syncthreads();
        float basen, based;
        {
            float2 s0 = part[0][0][u], s1 = part[0][1][u];
            float2 s2 = part[0][2][u], s3 = part[0][3][u];
            basen = s0.x + s1.x + s2.x + s3.x + gnu;
            based = s0.y + s1.y + s2.y + s3.y + cdu;
        }

        int pb = 1;
        float accA = 0.0f, halt_sum = 0.0f, rem = 0.0f;
        int nupd = 0;

        // ---- ACT loop (uniform early exit) ----
#pragma unroll 1
        for (int n = 0; n < 10; ++n) {
#pragma unroll 1
            for (int uu = 0; uu < 6; ++uu) {
                float num = 0.f, den = 0.f;
                // register rows
#pragma unroll
                for (int m = 0; m < 24; ++m) {
                    float v0 = RLF(2 * m), v1 = RLF(2 * m + 1);
                    float s0 = sigz(rg_ab[2 * m], v0);
                    float s1 = sigz(rg_ab[2 * m + 1], v1);
                    accum(rg_w2[m], s0, s1, num, den);
                }
                // LDS rows
#pragma unroll
                for (int m = 0; m < 8; ++m) {
                    unsigned int ab0 = ab_lds[(16 * qi + 2 * m) * UU + j];
                    unsigned int ab1 = ab_lds[(16 * qi + 2 * m + 1) * UU + j];
                    unsigned int wp  = w2_lds[(8 * qi + m) * UU + j];
                    float v0 = RLF(48 + 2 * m), v1 = RLF(48 + 2 * m + 1);
                    float s0 = sigz(ab0, v0);
                    float s1 = sigz(ab1, v1);
                    accum(wp, s0, s1, num, den);
                }
                part[pb][qi][j] = make_float2(num, den);
                __syncthreads();
                // redundant per-wave v-update for own units
                float2 p0 = part[pb][0][u], p1 = part[pb][1][u];
                float2 p2 = part[pb][2][u], p3 = part[pb][3][u];
                float tn = p0.x + p1.x + p2.x + p3.x + basen;
                float td = p0.y + p1.y + p2.y + p3.y + based;
                v = fmaf(cmtu, v, tn) * __builtin_amdgcn_rcpf(td);
                pb ^= 1;
            }

            // halting p = sigmoid(v . halt_w + hb); qj==0 waves hold all 256 units
            if (qj == 0) {
                float hp = v * hwu;
                hp += __shfl_down(hp, 32, 64);
                hp += __shfl_down(hp, 16, 64);
                hp += __shfl_down(hp, 8, 64);
                hp += __shfl_down(hp, 4, 64);
                hp += __shfl_down(hp, 2, 64);
                hp += __shfl_down(hp, 1, 64);
                if (l == 0) red[qi] = hp;
            }
            __syncthreads();
            float dot = red[0] + red[1] + red[2] + red[3] + hb;
            float pr = __builtin_amdgcn_rcpf(1.0f + __builtin_amdgcn_exp2f(-dot * LOG2E));
            float new_sum = halt_sum + pr;
            bool halting = (n == 9) || (new_sum >= 0.99f);
            float r = 1.0f - halt_sum;
            float wgt = halting ? r : pr;
            accA = fmaf(wgt, v, accA);
            if (halting) rem += r;
            halt_sum = new_sum;
            ++nupd;
            if (halting) break;
        }

        // ---- t epilogue: new_state = accA ----
        if (qj == 0)
            readout[((size_t)b * TT + t) * UU + u] = fmaf(accA, owu, obu);
        v = accA;
        pond += (float)nupd + rem;
    }

    if (qj == 0) h_state[(size_t)b * UU + u] = v;
    if (tid == 0) atomicAdd(ponder_out, pond * (1.0f / BB));
}

// ---------------- launch ----------------
extern "C" void kernel_launch(void* const* d_in, const int* in_sizes, int n_in,
                              void* d_out, int out_size, void* d_ws, size_t ws_size,
                              hipStream_t stream)
{
    const float* x             = (const float*)d_in[0];
    const float* input_w       = (const float*)d_in[1];
    const float* input_b       = (const float*)d_in[2];
    const float* sensory_w     = (const float*)d_in[3];
    const float* sensory_mu    = (const float*)d_in[4];
    const float* sensory_sigma = (const float*)d_in[5];
    const float* sensory_erev  = (const float*)d_in[6];
    const float* w             = (const float*)d_in[7];
    const float* mu            = (const float*)d_in[8];
    const float* sigma         = (const float*)d_in[9];
    const float* erev          = (const float*)d_in[10];
    const float* gleak         = (const float*)d_in[11];
    const float* vleak         = (const float*)d_in[12];
    const float* cm            = (const float*)d_in[13];
    const float* output_w      = (const float*)d_in[14];
    const float* output_b      = (const float*)d_in[15];
    const float* halt_w        = (const float*)d_in[16];
    const float* halt_b        = (const float*)d_in[17];

    float* readout = (float*)d_out;
    float* h_state = readout + (size_t)BB * TT * UU;
    float* ponder  = h_state + (size_t)BB * UU;

    char* wsb = (char*)d_ws;
    unsigned int* rab = (unsigned int*)wsb;  wsb += (size_t)UU * UU * 4;
    unsigned int* rw2 = (unsigned int*)wsb;  wsb += (size_t)(UU / 2) * UU * 4;
    unsigned int* sab = (unsigned int*)wsb;  wsb += (size_t)SS * UU * 4;
    unsigned int* sw2 = (unsigned int*)wsb;  wsb += (size_t)(SS / 2) * UU * 4;
    float* cmt  = (float*)wsb;  wsb += (size_t)UU * 4;
    float* gnum = (float*)wsb;  wsb += (size_t)UU * 4;
    float* cden = (float*)wsb;  wsb += (size_t)UU * 4;

    hipMemsetAsync(ponder, 0, sizeof(float), stream);
    prep_kernel<<<(UU * UU) / 256, 256, 0, stream>>>(
        sensory_w, sensory_mu, sensory_sigma, sensory_erev,
        w, mu, sigma, erev, gleak, vleak, cm,
        rab, rw2, sab, sw2, cmt, gnum, cden);
    ltc_kernel<<<BB, 1024, 0, stream>>>(
        x, input_w, input_b, halt_w, halt_b, output_w, output_b,
        rab, rw2, sab, sw2, cmt, gnum, cden,
        readout, h_state, ponder);
}